// Round 3
// baseline (322.162 us; speedup 1.0000x reference)
//
#include <hip/hip_runtime.h>
#include <hip/hip_bf16.h>

#define N_ROWS 262144
#define D_IN 162
#define H_DIM 256
#define K_DIM 30
#define ROWS 32          // rows per block

using bf16_t = __hip_bfloat16;
typedef __attribute__((ext_vector_type(8))) short bf16x8;
typedef __attribute__((ext_vector_type(4))) float f32x4;

// bf16-element index into a swizzled LDS tile with 256-col (512 B) row stride.
// XOR spreads 8 consecutive rows across 8 distinct 16B slots.
// NOTE: stride is hard-coded at 512 B -- every buffer indexed through this
// helper MUST be allocated with 256 bf16 columns per row.
__device__ __forceinline__ int swz_idx(int row, int col) {
  int byte = (row << 9) + (col << 1);
  byte ^= (row & 7) << 4;
  return byte >> 1;
}

__device__ __forceinline__ float softplus_f(float x) {
  return (x > 15.f) ? x : log1pf(__expf(x));
}

// ---------------- weight packing: fp32 [K][N] -> bf16 [kb][Np][32] ------------
__global__ void pack_b_kernel(const float* __restrict__ src, bf16_t* __restrict__ dst,
                              int K, int N, int Np, int KB) {
  int idx = blockIdx.x * 256 + threadIdx.x;
  int total = KB * Np * 32;
  if (idx >= total) return;
  int ks = idx & 31;
  int n  = (idx >> 5) % Np;
  int kb = idx / (32 * Np);
  int k  = kb * 32 + ks;
  float v = (k < K && n < N) ? src[k * N + n] : 0.f;
  dst[idx] = __float2bfloat16(v);
}

// Wa|Wb side by side: cols 0..29 = Wa, 32..61 = Wb.
__global__ void pack_ab_kernel(const float* __restrict__ Wa, const float* __restrict__ Wb,
                               bf16_t* __restrict__ dst) {
  int idx = blockIdx.x * 256 + threadIdx.x;   // total 8*64*32 = 16384
  if (idx >= 8 * 64 * 32) return;
  int ks = idx & 31;
  int n  = (idx >> 5) & 63;
  int kb = idx >> 11;
  int k  = kb * 32 + ks;
  float v = 0.f;
  if (n < 30)                 v = Wa[k * 30 + n];
  else if (n >= 32 && n < 62) v = Wb[k * 30 + (n - 32)];
  dst[idx] = __float2bfloat16(v);
}

// ---------------- fused forward ------------------------------------------------
__launch_bounds__(256, 4)
__global__ void usdn_fused(const float* __restrict__ Yh, const float* __restrict__ u,
                           const float* __restrict__ b1, const float* __restrict__ b2,
                           const float* __restrict__ ba, const float* __restrict__ bb,
                           const float* __restrict__ bd1, const float* __restrict__ bd2,
                           const bf16_t* __restrict__ Wp1, const bf16_t* __restrict__ Wp2,
                           const bf16_t* __restrict__ Wpab, const bf16_t* __restrict__ Wpd1,
                           const bf16_t* __restrict__ Wpd2,
                           float* __restrict__ outRecon, float* __restrict__ outAlpha,
                           float* __restrict__ outBeta, float* __restrict__ outPi) {
  __shared__ bf16_t bufY[ROWS * 256];   // 16 KB: Yh(K<=192) | vbuf fp32[32][33] | piT
  __shared__ bf16_t bufH[ROWS * 256];   // 16 KB: h1 -> h2 (in-place) -> d

  const int tid = threadIdx.x;
  const int w  = tid >> 6;
  const int l  = tid & 63;
  const int lr = l & 15;
  const int lg = l >> 4;
  const int r0 = blockIdx.x * ROWS;

  // ---- stage Yh tile (32 x 162 fp32 contiguous) -> bufY bf16, zero-pad to 192
  {
    const float4* src = reinterpret_cast<const float4*>(Yh + (size_t)r0 * D_IN);
#pragma unroll
    for (int it = 0; it < 6; ++it) {
      int i = tid + it * 256;
      if (i < (ROWS * D_IN) / 4) {
        float4 f = src[i];
        int base = i << 2;
#pragma unroll
        for (int e = 0; e < 4; ++e) {
          int idx = base + e;
          int row = idx / D_IN;          // magic-mul, compile-time constant
          int col = idx - row * D_IN;
          bufY[swz_idx(row, col)] = __float2bfloat16((&f.x)[e]);
        }
      }
    }
    // pad cols 162..191
    for (int i = tid; i < ROWS * 30; i += 256) {
      int row = i / 30;
      int col = D_IN + (i - row * 30);
      bufY[swz_idx(row, col)] = __float2bfloat16(0.f);
    }
  }
  __syncthreads();

  // ---- GEMM1: h1 = relu(Yh @ W1 + b1), K=192 -> bufH. wave w: cols 64w..64w+63
  {
    f32x4 acc[2][4] = {};
#pragma unroll
    for (int kb = 0; kb < 6; ++kb) {
      bf16x8 a[2], b[4];
#pragma unroll
      for (int m = 0; m < 2; ++m)
        a[m] = *reinterpret_cast<const bf16x8*>(bufY + swz_idx(16 * m + lr, kb * 32 + 8 * lg));
#pragma unroll
      for (int n = 0; n < 4; ++n)
        b[n] = *reinterpret_cast<const bf16x8*>(Wp1 + ((kb * 256 + w * 64 + 16 * n + lr) << 5) + 8 * lg);
#pragma unroll
      for (int m = 0; m < 2; ++m)
#pragma unroll
        for (int n = 0; n < 4; ++n)
          acc[m][n] = __builtin_amdgcn_mfma_f32_16x16x32_bf16(a[m], b[n], acc[m][n], 0, 0, 0);
    }
#pragma unroll
    for (int n = 0; n < 4; ++n) {
      int col = w * 64 + 16 * n + lr;
      float bv = b1[col];
#pragma unroll
      for (int m = 0; m < 2; ++m)
#pragma unroll
        for (int i = 0; i < 4; ++i) {
          float x = fmaxf(acc[m][n][i] + bv, 0.f);
          bufH[swz_idx(16 * m + 4 * lg + i, col)] = __float2bfloat16(x);
        }
    }
  }
  __syncthreads();

  // ---- GEMM2: h2 = relu(h1 @ W2 + b2), K=256, IN-PLACE into bufH
  {
    f32x4 acc[2][4] = {};
#pragma unroll
    for (int kb = 0; kb < 8; ++kb) {
      bf16x8 a[2], b[4];
#pragma unroll
      for (int m = 0; m < 2; ++m)
        a[m] = *reinterpret_cast<const bf16x8*>(bufH + swz_idx(16 * m + lr, kb * 32 + 8 * lg));
#pragma unroll
      for (int n = 0; n < 4; ++n)
        b[n] = *reinterpret_cast<const bf16x8*>(Wp2 + ((kb * 256 + w * 64 + 16 * n + lr) << 5) + 8 * lg);
#pragma unroll
      for (int m = 0; m < 2; ++m)
#pragma unroll
        for (int n = 0; n < 4; ++n)
          acc[m][n] = __builtin_amdgcn_mfma_f32_16x16x32_bf16(a[m], b[n], acc[m][n], 0, 0, 0);
    }
    __syncthreads();   // all reads of h1 done -> safe to overwrite
#pragma unroll
    for (int n = 0; n < 4; ++n) {
      int col = w * 64 + 16 * n + lr;
      float bv = b2[col];
#pragma unroll
      for (int m = 0; m < 2; ++m)
#pragma unroll
        for (int i = 0; i < 4; ++i) {
          float x = fmaxf(acc[m][n][i] + bv, 0.f);
          bufH[swz_idx(16 * m + 4 * lg + i, col)] = __float2bfloat16(x);
        }
    }
  }
  __syncthreads();

  // ---- heads: alpha/beta = softplus(h2 @ [Wa|Wb] + bias) + eps; v -> vbuf
  // waves 0,1: wave w owns rows 16w..16w+15, 64 packed cols.
  if (w < 2) {
    f32x4 acc3[4] = {};
#pragma unroll
    for (int kb = 0; kb < 8; ++kb) {
      bf16x8 a = *reinterpret_cast<const bf16x8*>(bufH + swz_idx(16 * w + lr, kb * 32 + 8 * lg));
#pragma unroll
      for (int n = 0; n < 4; ++n) {
        bf16x8 b = *reinterpret_cast<const bf16x8*>(Wpab + ((kb * 64 + 16 * n + lr) << 5) + 8 * lg);
        acc3[n] = __builtin_amdgcn_mfma_f32_16x16x32_bf16(a, b, acc3[n], 0, 0, 0);
      }
    }
    float uu  = u[0] * 0.98f + 0.01f;
    float l2u = log2f(uu);
    float* vbuf = reinterpret_cast<float*>(bufY);   // bufY (Yh) is dead
#pragma unroll
    for (int n = 0; n < 2; ++n) {
      int j = 16 * n + lr;
      bool valid = (j < K_DIM);
      float bva = valid ? ba[j] : 0.f;
      float bvb = valid ? bb[j] : 0.f;
#pragma unroll
      for (int i = 0; i < 4; ++i) {
        int row = 16 * w + 4 * lg + i;
        if (valid) {
          float alpha = softplus_f(acc3[n][i] + bva) + 1e-4f;
          float beta  = softplus_f(acc3[n + 2][i] + bvb) + 1e-4f;
          size_t gro = (size_t)(r0 + row);
          outAlpha[gro * K_DIM + j] = alpha;
          outBeta [gro * K_DIM + j] = beta;
          float v;
          if (j == K_DIM - 1) v = 1.f;
          else {
            float t = exp2f(l2u / beta);          // uu^(1/beta)
            v = exp2f(log2f(1.f - t) / alpha);    // (1-t)^(1/alpha)
          }
          vbuf[row * 33 + j] = v;
        }
      }
    }
  }
  __syncthreads();

  // ---- stick-breaking scan: thread t<32 owns row t; pi -> outPi + piT(bf16)
  {
    bf16_t* piT = bufY + 4096;                    // byte offset 8192, clear of vbuf (4224 B)
    if (tid < ROWS) {
      const float* vbuf = reinterpret_cast<const float*>(bufY);
      int row = tid;
      size_t gro = (size_t)(r0 + row);
      float ex = 1.f;
#pragma unroll
      for (int j = 0; j < K_DIM - 1; ++j) {
        float vj = vbuf[row * 33 + j];
        float pi = vj * ex;
        outPi[gro * K_DIM + j] = pi;
        piT[row * 40 + j] = __float2bfloat16(pi);
        ex *= (1.f - vj);
      }
      outPi[gro * K_DIM + (K_DIM - 1)] = ex;      // v_K = 1
      piT[row * 40 + 29] = __float2bfloat16(ex);
      piT[row * 40 + 30] = __float2bfloat16(0.f);
      piT[row * 40 + 31] = __float2bfloat16(0.f);
    }
  }
  __syncthreads();

  // ---- GEMM4: d = relu(pi @ Wd1 + bd1), K=32 -> bufH (h2 dead, last read 2 barriers ago)
  {
    const bf16_t* piT = bufY + 4096;
    f32x4 acc[2][4] = {};
    bf16x8 a[2];
#pragma unroll
    for (int m = 0; m < 2; ++m)
      a[m] = *reinterpret_cast<const bf16x8*>(piT + (16 * m + lr) * 40 + 8 * lg);
#pragma unroll
    for (int n = 0; n < 4; ++n) {
      bf16x8 b = *reinterpret_cast<const bf16x8*>(Wpd1 + ((w * 64 + 16 * n + lr) << 5) + 8 * lg);
#pragma unroll
      for (int m = 0; m < 2; ++m)
        acc[m][n] = __builtin_amdgcn_mfma_f32_16x16x32_bf16(a[m], b, acc[m][n], 0, 0, 0);
    }
#pragma unroll
    for (int n = 0; n < 4; ++n) {
      int col = w * 64 + 16 * n + lr;
      float bv = bd1[col];
#pragma unroll
      for (int m = 0; m < 2; ++m)
#pragma unroll
        for (int i = 0; i < 4; ++i) {
          float x = fmaxf(acc[m][n][i] + bv, 0.f);
          bufH[swz_idx(16 * m + 4 * lg + i, col)] = __float2bfloat16(x);
        }
    }
  }
  __syncthreads();

  // ---- GEMM5: recon = sigmoid(d @ Wd2 + bd2); wave w: cols 48w..48w+47 (pad 192)
  {
    f32x4 acc[2][3] = {};
#pragma unroll
    for (int kb = 0; kb < 8; ++kb) {
      bf16x8 a[2];
#pragma unroll
      for (int m = 0; m < 2; ++m)
        a[m] = *reinterpret_cast<const bf16x8*>(bufH + swz_idx(16 * m + lr, kb * 32 + 8 * lg));
#pragma unroll
      for (int n = 0; n < 3; ++n) {
        bf16x8 b = *reinterpret_cast<const bf16x8*>(Wpd2 + ((kb * 192 + w * 48 + 16 * n + lr) << 5) + 8 * lg);
#pragma unroll
        for (int m = 0; m < 2; ++m)
          acc[m][n] = __builtin_amdgcn_mfma_f32_16x16x32_bf16(a[m], b, acc[m][n], 0, 0, 0);
      }
    }
#pragma unroll
    for (int n = 0; n < 3; ++n) {
      int col = w * 48 + 16 * n + lr;
      if (col < D_IN) {
        float bv = bd2[col];
#pragma unroll
        for (int m = 0; m < 2; ++m)
#pragma unroll
          for (int i = 0; i < 4; ++i) {
            int row = 16 * m + 4 * lg + i;
            float x = acc[m][n][i] + bv;
            float s = 1.f / (1.f + __expf(-x));
            outRecon[(size_t)(r0 + row) * D_IN + col] = s;
          }
      }
    }
  }
}

extern "C" void kernel_launch(void* const* d_in, const int* in_sizes, int n_in,
                              void* d_out, int out_size, void* d_ws, size_t ws_size,
                              hipStream_t stream) {
  const float* Yh  = (const float*)d_in[0];
  const float* u   = (const float*)d_in[1];
  const float* W1  = (const float*)d_in[2];
  const float* b1  = (const float*)d_in[3];
  const float* W2  = (const float*)d_in[4];
  const float* b2  = (const float*)d_in[5];
  const float* Wa  = (const float*)d_in[6];
  const float* ba  = (const float*)d_in[7];
  const float* Wb  = (const float*)d_in[8];
  const float* bb  = (const float*)d_in[9];
  const float* Wd1 = (const float*)d_in[10];
  const float* bd1 = (const float*)d_in[11];
  const float* Wd2 = (const float*)d_in[12];
  const float* bd2 = (const float*)d_in[13];

  bf16_t* ws   = (bf16_t*)d_ws;
  bf16_t* Wp1  = ws;                  // 6*256*32 = 49152 elems
  bf16_t* Wp2  = Wp1 + 49152;         // 8*256*32 = 65536
  bf16_t* Wpab = Wp2 + 65536;         // 8*64*32  = 16384
  bf16_t* Wpd1 = Wpab + 16384;        // 1*256*32 = 8192
  bf16_t* Wpd2 = Wpd1 + 8192;         // 8*192*32 = 49152

  float* outRecon = (float*)d_out;
  float* outAlpha = outRecon + (size_t)N_ROWS * D_IN;
  float* outBeta  = outAlpha + (size_t)N_ROWS * K_DIM;
  float* outPi    = outBeta  + (size_t)N_ROWS * K_DIM;

  pack_b_kernel<<<192, 256, 0, stream>>>(W1, Wp1, 162, 256, 256, 6);
  pack_b_kernel<<<256, 256, 0, stream>>>(W2, Wp2, 256, 256, 256, 8);
  pack_ab_kernel<<<64, 256, 0, stream>>>(Wa, Wb, Wpab);
  pack_b_kernel<<<32, 256, 0, stream>>>(Wd1, Wpd1, 30, 256, 256, 1);
  pack_b_kernel<<<192, 256, 0, stream>>>(Wd2, Wpd2, 256, 162, 192, 8);

  usdn_fused<<<N_ROWS / ROWS, 256, 0, stream>>>(Yh, u, b1, b2, ba, bb, bd1, bd2,
                                                Wp1, Wp2, Wpab, Wpd1, Wpd2,
                                                outRecon, outAlpha, outBeta, outPi);
}

// Round 4
// 280.702 us; speedup vs baseline: 1.1477x; 1.1477x over previous
//
#include <hip/hip_runtime.h>
#include <hip/hip_bf16.h>

#define N_ROWS 262144
#define D_IN 162
#define K_DIM 30
#define ROWS 32          // rows per block

using bf16_t = __hip_bfloat16;
typedef __attribute__((ext_vector_type(8))) short bf16x8;
typedef __attribute__((ext_vector_type(4))) float f32x4;

// byte offset into a swizzled LDS tile: row stride 512 B, col in bf16 elems.
// XOR of (row&7) into byte bits 4-6 spreads 8 consecutive rows across 8
// distinct 16B slots -> 2-way (free) on 16-lane column reads.
__device__ __forceinline__ int swz_byte(int row, int col) {
  int b = (row << 9) + (col << 1);
  return b ^ ((row & 7) << 4);
}

__device__ __forceinline__ uint32_t bf16b(float x) {
  return (uint32_t)__builtin_bit_cast(unsigned short, __float2bfloat16(x));
}
__device__ __forceinline__ uint32_t pack2(float lo, float hi) {
  return bf16b(lo) | (bf16b(hi) << 16);   // compiler fuses to v_cvt_pk_bf16_f32
}
__device__ __forceinline__ float unpk_lo(uint32_t p) {
  return __bfloat162float(__builtin_bit_cast(__hip_bfloat16, (unsigned short)(p & 0xffff)));
}
__device__ __forceinline__ float unpk_hi(uint32_t p) {
  return __bfloat162float(__builtin_bit_cast(__hip_bfloat16, (unsigned short)(p >> 16)));
}
__device__ __forceinline__ float softplus_f(float x) {
  return (x > 15.f) ? x : log1pf(__expf(x));
}

// ---------------- weight packing: fp32 [K][N] -> bf16 [kb][Np][32] ------------
// element (k,n) at ((k/32)*Np + n)*32 + (k%32): one contiguous 16B frag per lane
__global__ void pack_b_kernel(const float* __restrict__ src, bf16_t* __restrict__ dst,
                              int K, int N, int Np, int KB) {
  int idx = blockIdx.x * 256 + threadIdx.x;
  int total = KB * Np * 32;
  if (idx >= total) return;
  int ks = idx & 31;
  int n  = (idx >> 5) % Np;
  int kb = idx / (32 * Np);
  int k  = kb * 32 + ks;
  float v = (k < K && n < N) ? src[k * N + n] : 0.f;
  dst[idx] = __float2bfloat16(v);
}

// Wa/Wb INTERLEAVED: out-col 2j = Wa[:,j], 2j+1 = Wb[:,j]  (j<30; 60..63 zero).
// With swapped-operand MFMA each lane's 4 consecutive out-cols are then
// {alpha_j, beta_j, alpha_{j+1}, beta_{j+1}} -> v computable in-register.
__global__ void pack_ab_kernel(const float* __restrict__ Wa, const float* __restrict__ Wb,
                               bf16_t* __restrict__ dst) {
  int idx = blockIdx.x * 256 + threadIdx.x;   // total 8*64*32 = 16384
  if (idx >= 8 * 64 * 32) return;
  int ks = idx & 31;
  int n  = (idx >> 5) & 63;
  int kb = idx >> 11;
  int k  = kb * 32 + ks;
  int j = n >> 1, s = n & 1;
  float v = (j < K_DIM) ? (s ? Wb[k * K_DIM + j] : Wa[k * K_DIM + j]) : 0.f;
  dst[idx] = __float2bfloat16(v);
}

// ---------------- swapped-operand GEMM core -----------------------------------
// D'[oc][row] = sum_k W[k][oc] * X[row][k].  A'-frag = packed W (lane: oc=16mo+lr,
// k contiguous), B'-frag = LDS tile (lane: row=16nr+lr, k contiguous).  D'-frag
// (m89 layout): lane holds oc = 16mo+4lg+i (4 consecutive out-cols), row = lr+16nr.
template<int KB, int NP, int NMO>
__device__ __forceinline__ void gemm_acc(const uint8_t* lds, int srcOff,
                                         const bf16_t* __restrict__ Wp, int ocBase,
                                         int lr, int lg, f32x4 (&acc)[NMO][2]) {
  int bE[2], bO[2];   // even/odd-kb bases: 128B k-pair steps commute with row-XOR
#pragma unroll
  for (int nr = 0; nr < 2; ++nr) {
    bE[nr] = srcOff + swz_byte(16 * nr + lr, 8 * lg);
    bO[nr] = srcOff + swz_byte(16 * nr + lr, 32 + 8 * lg);
  }
#pragma unroll
  for (int kb = 0; kb < KB; ++kb) {
    bf16x8 wf[NMO];
#pragma unroll
    for (int mo = 0; mo < NMO; ++mo)
      wf[mo] = *reinterpret_cast<const bf16x8*>(Wp + ((kb * NP + ocBase + 16 * mo + lr) << 5) + 8 * lg);
    bf16x8 hf[2];
#pragma unroll
    for (int nr = 0; nr < 2; ++nr) {
      int base = (kb & 1) ? bO[nr] : bE[nr];
      hf[nr] = *reinterpret_cast<const bf16x8*>(lds + base + (kb >> 1) * 128);
    }
#pragma unroll
    for (int mo = 0; mo < NMO; ++mo)
#pragma unroll
      for (int nr = 0; nr < 2; ++nr)
        acc[mo][nr] = __builtin_amdgcn_mfma_f32_16x16x32_bf16(wf[mo], hf[nr], acc[mo][nr], 0, 0, 0);
  }
}

// acc init from bias (bias indexes the out-col dim = 4 consecutive per lane)
template<int NMO>
__device__ __forceinline__ void acc_bias_init(const float* __restrict__ bias, int ocBase,
                                              int lg, f32x4 (&acc)[NMO][2]) {
#pragma unroll
  for (int mo = 0; mo < NMO; ++mo) {
    float4 bv = *reinterpret_cast<const float4*>(bias + ocBase + 16 * mo + 4 * lg);
    f32x4 t = {bv.x, bv.y, bv.z, bv.w};
#pragma unroll
    for (int nr = 0; nr < 2; ++nr) acc[mo][nr] = t;
  }
}

// relu -> packed bf16x4 -> single ds_write_b64 per fragment
template<int NMO>
__device__ __forceinline__ void epi_relu_store(uint8_t* lds, int dstOff, int ocBase,
                                               int lr, int lg, f32x4 (&acc)[NMO][2]) {
#pragma unroll
  for (int mo = 0; mo < NMO; ++mo)
#pragma unroll
    for (int nr = 0; nr < 2; ++nr) {
      int row = 16 * nr + lr;
      int col = ocBase + 16 * mo + 4 * lg;
      float x0 = fmaxf(acc[mo][nr][0], 0.f), x1 = fmaxf(acc[mo][nr][1], 0.f);
      float x2 = fmaxf(acc[mo][nr][2], 0.f), x3 = fmaxf(acc[mo][nr][3], 0.f);
      uint2 p; p.x = pack2(x0, x1); p.y = pack2(x2, x3);
      *reinterpret_cast<uint2*>(lds + dstOff + swz_byte(row, col)) = p;  // 8B within one 16B swz unit
    }
}

// ---------------- fused forward ------------------------------------------------
#define OFF_H 16384      // bufH at 16KB; bufY at 0
#define OFF_PI 8192      // piT (bf16, row stride 80B) inside dead bufY
__launch_bounds__(256, 4)
__global__ void usdn_fused(const float* __restrict__ Yh, const float* __restrict__ u,
                           const float* __restrict__ b1, const float* __restrict__ b2,
                           const float* __restrict__ ba, const float* __restrict__ bb,
                           const float* __restrict__ bd1, const float* __restrict__ bd2,
                           const bf16_t* __restrict__ Wp1, const bf16_t* __restrict__ Wp2,
                           const bf16_t* __restrict__ Wpab, const bf16_t* __restrict__ Wpd1,
                           const bf16_t* __restrict__ Wpd2,
                           float* __restrict__ outRecon, float* __restrict__ outAlpha,
                           float* __restrict__ outBeta, float* __restrict__ outPi) {
  __shared__ __align__(16) uint8_t lds[32768];

  const int tid = threadIdx.x;
  const int w  = tid >> 6;
  const int l  = tid & 63;
  const int lr = l & 15;
  const int lg = l >> 4;
  const int r0 = blockIdx.x * ROWS;

  // ---- stage Yh tile: row-aligned float2 loads, packed bf16x2 LDS writes
  {
    int row = tid >> 3, l8 = tid & 7;
    const float2* src = reinterpret_cast<const float2*>(Yh + (size_t)(r0 + row) * D_IN);
#pragma unroll
    for (int it = 0; it < 12; ++it) {
      int f2 = l8 + it * 8;                 // float2 index within row (81 real, pad to 96)
      uint32_t p = 0;
      if (f2 < 81) { float2 v = src[f2]; p = pack2(v.x, v.y); }
      if (f2 < 96) *reinterpret_cast<uint32_t*>(lds + swz_byte(row, f2 * 2)) = p;
    }
  }
  __syncthreads();

  // ---- GEMM1: h1 = relu(W1^T x^T + b1), K=192 -> bufH (wave w: out-cols 64w..)
  {
    f32x4 acc[4][2];
    acc_bias_init<4>(b1, w * 64, lg, acc);
    gemm_acc<6, 256, 4>(lds, 0, Wp1, w * 64, lr, lg, acc);
    epi_relu_store<4>(lds, OFF_H, w * 64, lr, lg, acc);
  }
  __syncthreads();

  // ---- GEMM2: h2 = relu(W2^T h1^T + b2), K=256, IN-PLACE in bufH
  {
    f32x4 acc[4][2];
    acc_bias_init<4>(b2, w * 64, lg, acc);
    gemm_acc<8, 256, 4>(lds, OFF_H, Wp2, w * 64, lr, lg, acc);
    __syncthreads();               // all h1 reads done (LDS-only drain)
    epi_relu_store<4>(lds, OFF_H, w * 64, lr, lg, acc);
  }
  __syncthreads();

  // ---- heads: wave w owns out-cols 16w..16w+15 = {a,b} pairs for j=8w..8w+7
  float regA0[2], regA1[2], regB0[2], regB1[2];   // alpha/beta kept for deferred store
  int   j0 = 8 * w + 2 * lg;
  {
    bool jv = (j0 < K_DIM);                       // j0 even; j0<30 -> j0+1<=29 valid
    float ba0 = jv ? ba[j0] : 0.f,     bb0 = jv ? bb[j0] : 0.f;
    float ba1 = jv ? ba[j0 + 1] : 0.f, bb1 = jv ? bb[j0 + 1] : 0.f;
    f32x4 acc[1][2];
    f32x4 binit = {ba0, bb0, ba1, bb1};
    acc[0][0] = binit; acc[0][1] = binit;
    gemm_acc<8, 64, 1>(lds, OFF_H, Wpab, 16 * w, lr, lg, acc);

    float uu  = u[0] * 0.98f + 0.01f;
    float l2u = log2f(uu);
    float* vbuf = reinterpret_cast<float*>(lds);  // bufY dead; fp32 [32][33]
#pragma unroll
    for (int nr = 0; nr < 2; ++nr) {
      int row = 16 * nr + lr;
      float a0 = softplus_f(acc[0][nr][0]) + 1e-4f;
      float b0v = softplus_f(acc[0][nr][1]) + 1e-4f;
      float a1 = softplus_f(acc[0][nr][2]) + 1e-4f;
      float b1v = softplus_f(acc[0][nr][3]) + 1e-4f;
      regA0[nr] = a0; regB0[nr] = b0v; regA1[nr] = a1; regB1[nr] = b1v;
      if (jv) {
        if (j0 < K_DIM - 1) {                     // v only needed for j<=28
          float t = exp2f(l2u / b0v);
          vbuf[row * 33 + j0] = exp2f(log2f(1.f - t) / a0);
        }
        if (j0 + 1 < K_DIM - 1) {
          float t = exp2f(l2u / b1v);
          vbuf[row * 33 + j0 + 1] = exp2f(log2f(1.f - t) / a1);
        }
      }
    }
  }
  __syncthreads();

  // ---- stick-breaking scan: thread t<32 owns row t; pi -> piT (bf16, LDS only)
  if (tid < ROWS) {
    const float* vbuf = reinterpret_cast<const float*>(lds);
    bf16_t* piT = reinterpret_cast<bf16_t*>(lds + OFF_PI);
    int row = tid;
    float ex = 1.f;
#pragma unroll
    for (int j = 0; j < K_DIM - 1; ++j) {
      float vj = vbuf[row * 33 + j];
      float pi = vj * ex;
      piT[row * 40 + j] = __float2bfloat16(pi);
      ex *= (1.f - vj);
    }
    piT[row * 40 + (K_DIM - 1)] = __float2bfloat16(ex);   // v_K = 1
    piT[row * 40 + 30] = __float2bfloat16(0.f);           // pad K to 32
    piT[row * 40 + 31] = __float2bfloat16(0.f);
  }
  __syncthreads();

  // ---- GEMM4: d = relu(Wd1^T pi^T + bd1), K=32 -> bufH (h2 dead 2 barriers ago)
  {
    f32x4 acc[4][2];
    acc_bias_init<4>(bd1, w * 64, lg, acc);
    bf16x8 pf[2];
#pragma unroll
    for (int nr = 0; nr < 2; ++nr)
      pf[nr] = *reinterpret_cast<const bf16x8*>(lds + OFF_PI + (16 * nr + lr) * 80 + 16 * lg);
#pragma unroll
    for (int mo = 0; mo < 4; ++mo) {
      bf16x8 wf = *reinterpret_cast<const bf16x8*>(Wpd1 + ((w * 64 + 16 * mo + lr) << 5) + 8 * lg);
#pragma unroll
      for (int nr = 0; nr < 2; ++nr)
        acc[mo][nr] = __builtin_amdgcn_mfma_f32_16x16x32_bf16(wf, pf[nr], acc[mo][nr], 0, 0, 0);
    }
    epi_relu_store<4>(lds, OFF_H, w * 64, lr, lg, acc);
  }
  __syncthreads();

  // ---- GEMM5: recon = sigmoid(Wd2^T d^T + bd2); wave w: out-cols 48w.. (pad 192)
  {
    f32x4 acc[3][2];
#pragma unroll
    for (int mo = 0; mo < 3; ++mo) {
      int col0 = 48 * w + 16 * mo + 4 * lg;
      f32x4 t;
#pragma unroll
      for (int i = 0; i < 4; ++i) t[i] = (col0 + i < D_IN) ? bd2[col0 + i] : 0.f;
#pragma unroll
      for (int nr = 0; nr < 2; ++nr) acc[mo][nr] = t;
    }
    gemm_acc<8, 192, 3>(lds, OFF_H, Wpd2, 48 * w, lr, lg, acc);
#pragma unroll
    for (int mo = 0; mo < 3; ++mo) {
      int col0 = 48 * w + 16 * mo + 4 * lg;
#pragma unroll
      for (int nr = 0; nr < 2; ++nr) {
        int row = 16 * nr + lr;
        float s0 = 1.f / (1.f + __expf(-acc[mo][nr][0]));
        float s1 = 1.f / (1.f + __expf(-acc[mo][nr][1]));
        float s2 = 1.f / (1.f + __expf(-acc[mo][nr][2]));
        float s3 = 1.f / (1.f + __expf(-acc[mo][nr][3]));
        float* dst = outRecon + (size_t)(r0 + row) * D_IN + col0;
        if (col0 < D_IN)     *reinterpret_cast<float2*>(dst)     = make_float2(s0, s1);
        if (col0 + 2 < D_IN) *reinterpret_cast<float2*>(dst + 2) = make_float2(s2, s3);
      }
    }
  }

  // ---- deferred global stores (after last barrier; no further syncs) ----
  // alpha/beta from registers: float2 per row (j0 even -> 8B aligned)
  if (j0 < K_DIM) {
#pragma unroll
    for (int nr = 0; nr < 2; ++nr) {
      int row = 16 * nr + lr;
      size_t base = (size_t)(r0 + row) * K_DIM + j0;
      *reinterpret_cast<float2*>(outAlpha + base) = make_float2(regA0[nr], regA1[nr]);
      *reinterpret_cast<float2*>(outBeta  + base) = make_float2(regB0[nr], regB1[nr]);
    }
  }
  // pi re-read from piT (bf16 ok: |pi|<=1, err ~4e-3 < 2e-2 threshold), coalesced f2
  {
    int row = tid >> 3, l8 = tid & 7;
#pragma unroll
    for (int half = 0; half < 2; ++half) {
      int f2 = l8 + half * 8;
      if (f2 < 15) {
        uint32_t pp = *reinterpret_cast<const uint32_t*>(lds + OFF_PI + row * 80 + f2 * 4);
        *reinterpret_cast<float2*>(outPi + (size_t)(r0 + row) * K_DIM + f2 * 2) =
            make_float2(unpk_lo(pp), unpk_hi(pp));
      }
    }
  }
}

extern "C" void kernel_launch(void* const* d_in, const int* in_sizes, int n_in,
                              void* d_out, int out_size, void* d_ws, size_t ws_size,
                              hipStream_t stream) {
  const float* Yh  = (const float*)d_in[0];
  const float* u   = (const float*)d_in[1];
  const float* W1  = (const float*)d_in[2];
  const float* b1  = (const float*)d_in[3];
  const float* W2  = (const float*)d_in[4];
  const float* b2  = (const float*)d_in[5];
  const float* Wa  = (const float*)d_in[6];
  const float* ba  = (const float*)d_in[7];
  const float* Wb  = (const float*)d_in[8];
  const float* bb  = (const float*)d_in[9];
  const float* Wd1 = (const float*)d_in[10];
  const float* bd1 = (const float*)d_in[11];
  const float* Wd2 = (const float*)d_in[12];
  const float* bd2 = (const float*)d_in[13];

  bf16_t* ws   = (bf16_t*)d_ws;
  bf16_t* Wp1  = ws;                  // 6*256*32 = 49152 elems
  bf16_t* Wp2  = Wp1 + 49152;         // 8*256*32 = 65536
  bf16_t* Wpab = Wp2 + 65536;         // 8*64*32  = 16384 (interleaved a/b)
  bf16_t* Wpd1 = Wpab + 16384;        // 1*256*32 = 8192
  bf16_t* Wpd2 = Wpd1 + 8192;         // 8*192*32 = 49152

  float* outRecon = (float*)d_out;
  float* outAlpha = outRecon + (size_t)N_ROWS * D_IN;
  float* outBeta  = outAlpha + (size_t)N_ROWS * K_DIM;
  float* outPi    = outBeta  + (size_t)N_ROWS * K_DIM;

  pack_b_kernel<<<192, 256, 0, stream>>>(W1, Wp1, 162, 256, 256, 6);
  pack_b_kernel<<<256, 256, 0, stream>>>(W2, Wp2, 256, 256, 256, 8);
  pack_ab_kernel<<<64, 256, 0, stream>>>(Wa, Wb, Wpab);
  pack_b_kernel<<<32, 256, 0, stream>>>(Wd1, Wpd1, 30, 256, 256, 1);
  pack_b_kernel<<<192, 256, 0, stream>>>(Wd2, Wpd2, 256, 162, 192, 8);

  usdn_fused<<<N_ROWS / ROWS, 256, 0, stream>>>(Yh, u, b1, b2, ba, bb, bd1, bd2,
                                                Wp1, Wp2, Wpab, Wpd1, Wpd2,
                                                outRecon, outAlpha, outBeta, outPi);
}

// Round 5
// 269.854 us; speedup vs baseline: 1.1938x; 1.0402x over previous
//
#include <hip/hip_runtime.h>
#include <hip/hip_bf16.h>

#define N_ROWS 262144
#define D_IN 162
#define K_DIM 30
#define ROWS 32          // rows per block

using bf16_t = __hip_bfloat16;
typedef __attribute__((ext_vector_type(8))) short bf16x8;
typedef __attribute__((ext_vector_type(4))) float f32x4;

// byte offset into a swizzled LDS tile: row stride 512 B, col in bf16 elems.
// XOR of (row&7) into byte bits 4-6 spreads 8 consecutive rows across 8
// distinct 16B slots. NOTE: buffers using this must have 512 B row stride.
__device__ __forceinline__ int swz_byte(int row, int col) {
  int b = (row << 9) + (col << 1);
  return b ^ ((row & 7) << 4);
}

__device__ __forceinline__ uint32_t bf16b(float x) {
  return (uint32_t)__builtin_bit_cast(unsigned short, __float2bfloat16(x));
}
__device__ __forceinline__ uint32_t pack2(float lo, float hi) {
  return bf16b(lo) | (bf16b(hi) << 16);
}
__device__ __forceinline__ float unpk_lo(uint32_t p) {
  return __bfloat162float(__builtin_bit_cast(__hip_bfloat16, (unsigned short)(p & 0xffff)));
}
__device__ __forceinline__ float unpk_hi(uint32_t p) {
  return __bfloat162float(__builtin_bit_cast(__hip_bfloat16, (unsigned short)(p >> 16)));
}
__device__ __forceinline__ float softplus_f(float x) {
  return (x > 15.f) ? x : log1pf(__expf(x));
}

// ---------------- weight packing: fp32 [K][N] -> bf16 [kb][Np][32] ------------
__global__ void pack_b_kernel(const float* __restrict__ src, bf16_t* __restrict__ dst,
                              int K, int N, int Np, int KB) {
  int idx = blockIdx.x * 256 + threadIdx.x;
  int total = KB * Np * 32;
  if (idx >= total) return;
  int ks = idx & 31;
  int n  = (idx >> 5) % Np;
  int kb = idx / (32 * Np);
  int k  = kb * 32 + ks;
  float v = (k < K && n < N) ? src[k * N + n] : 0.f;
  dst[idx] = __float2bfloat16(v);
}

// Wa/Wb interleaved: out-col 2j = Wa[:,j], 2j+1 = Wb[:,j]
__global__ void pack_ab_kernel(const float* __restrict__ Wa, const float* __restrict__ Wb,
                               bf16_t* __restrict__ dst) {
  int idx = blockIdx.x * 256 + threadIdx.x;
  if (idx >= 8 * 64 * 32) return;
  int ks = idx & 31;
  int n  = (idx >> 5) & 63;
  int kb = idx >> 11;
  int k  = kb * 32 + ks;
  int j = n >> 1, s = n & 1;
  float v = (j < K_DIM) ? (s ? Wb[k * K_DIM + j] : Wa[k * K_DIM + j]) : 0.f;
  dst[idx] = __float2bfloat16(v);
}

// ---------------- weight fragment load (one kb, NMO out-col groups) -----------
template<int NP, int NMO>
__device__ __forceinline__ void wload(const bf16_t* __restrict__ Wp, int kb, int ocBase,
                                      int lr, int lg, bf16x8 (&out)[NMO]) {
#pragma unroll
  for (int mo = 0; mo < NMO; ++mo)
    out[mo] = *reinterpret_cast<const bf16x8*>(
        Wp + ((kb * NP + ocBase + 16 * mo + lr) << 5) + 8 * lg);
}

// ---------------- swapped-operand GEMM with rolling 2-kb weight prefetch ------
// wbuf must arrive preloaded with kb0 (slot 0) and kb1 (slot 1) — issued by the
// caller BEFORE the preceding __syncthreads so L2 latency hides under it.
template<int KB, int NP, int NMO>
__device__ __forceinline__ void gemm_roll(const uint8_t* lds, int srcOff,
                                          const bf16_t* __restrict__ Wp, int ocBase,
                                          int lr, int lg, f32x4 (&acc)[NMO][2],
                                          bf16x8 (&wbuf)[2][NMO]) {
  int bE[2], bO[2];   // even/odd-kb LDS bases (128B pair-steps commute with row-XOR)
#pragma unroll
  for (int nr = 0; nr < 2; ++nr) {
    bE[nr] = srcOff + swz_byte(16 * nr + lr, 8 * lg);
    bO[nr] = srcOff + swz_byte(16 * nr + lr, 32 + 8 * lg);
  }
#pragma unroll
  for (int kb = 0; kb < KB; ++kb) {
    bf16x8 cur[NMO];
#pragma unroll
    for (int mo = 0; mo < NMO; ++mo) cur[mo] = wbuf[kb & 1][mo];
    if (kb + 2 < KB)                       // compile-time (fully unrolled)
      wload<NP, NMO>(Wp, kb + 2, ocBase, lr, lg, wbuf[kb & 1]);
    bf16x8 hf[2];
#pragma unroll
    for (int nr = 0; nr < 2; ++nr) {
      int base = (kb & 1) ? bO[nr] : bE[nr];
      hf[nr] = *reinterpret_cast<const bf16x8*>(lds + base + (kb >> 1) * 128);
    }
#pragma unroll
    for (int mo = 0; mo < NMO; ++mo)
#pragma unroll
      for (int nr = 0; nr < 2; ++nr)
        acc[mo][nr] = __builtin_amdgcn_mfma_f32_16x16x32_bf16(cur[mo], hf[nr], acc[mo][nr], 0, 0, 0);
  }
}

template<int NMO>
__device__ __forceinline__ void acc_bias_init(const float* __restrict__ bias, int ocBase,
                                              int lg, f32x4 (&acc)[NMO][2]) {
#pragma unroll
  for (int mo = 0; mo < NMO; ++mo) {
    float4 bv = *reinterpret_cast<const float4*>(bias + ocBase + 16 * mo + 4 * lg);
    f32x4 t = {bv.x, bv.y, bv.z, bv.w};
#pragma unroll
    for (int nr = 0; nr < 2; ++nr) acc[mo][nr] = t;
  }
}

// relu -> packed bf16x4 -> one ds_write_b64 per fragment
template<int NMO>
__device__ __forceinline__ void epi_relu_store(uint8_t* lds, int dstOff, int ocBase,
                                               int lr, int lg, f32x4 (&acc)[NMO][2]) {
#pragma unroll
  for (int mo = 0; mo < NMO; ++mo)
#pragma unroll
    for (int nr = 0; nr < 2; ++nr) {
      int row = 16 * nr + lr;
      int col = ocBase + 16 * mo + 4 * lg;
      float x0 = fmaxf(acc[mo][nr][0], 0.f), x1 = fmaxf(acc[mo][nr][1], 0.f);
      float x2 = fmaxf(acc[mo][nr][2], 0.f), x3 = fmaxf(acc[mo][nr][3], 0.f);
      uint2 p; p.x = pack2(x0, x1); p.y = pack2(x2, x3);
      *reinterpret_cast<uint2*>(lds + dstOff + swz_byte(row, col)) = p;
    }
}

// ---------------- fused forward ------------------------------------------------
// LDS ping-pong: A = [0,16K) holds Yh -> h2 -> d ; B = [16K,32K) holds h1 ->
// {vbuf fp32[32][33] at +0, piT bf16 stride-80B at +8192}.
#define OFF_B  16384
#define OFF_PI (16384 + 8192)

__launch_bounds__(256, 4)
__global__ void usdn_fused(const float* __restrict__ Yh, const float* __restrict__ u,
                           const float* __restrict__ b1, const float* __restrict__ b2,
                           const float* __restrict__ ba, const float* __restrict__ bb,
                           const float* __restrict__ bd1, const float* __restrict__ bd2,
                           const bf16_t* __restrict__ Wp1, const bf16_t* __restrict__ Wp2,
                           const bf16_t* __restrict__ Wpab, const bf16_t* __restrict__ Wpd1,
                           const bf16_t* __restrict__ Wpd2,
                           float* __restrict__ outRecon, float* __restrict__ outAlpha,
                           float* __restrict__ outBeta, float* __restrict__ outPi) {
  __shared__ __align__(16) uint8_t lds[32768];

  const int tid = threadIdx.x;
  const int w  = tid >> 6;
  const int l  = tid & 63;
  const int lr = l & 15;
  const int lg = l >> 4;
  const int r0 = blockIdx.x * ROWS;

  // ---- stage Yh: issue all global loads first (regs), then prefetch G1 weights,
  // then pack+ds_write (which waits on the loads).
  const int srow = tid >> 3, sl8 = tid & 7;
  float2 sv[12];
  {
    const float2* src = reinterpret_cast<const float2*>(Yh + (size_t)(r0 + srow) * D_IN);
#pragma unroll
    for (int it = 0; it < 12; ++it) {
      int f2 = sl8 + it * 8;
      if (f2 < 81) sv[it] = src[f2];
    }
  }
  bf16x8 w1buf[2][4];
  wload<256, 4>(Wp1, 0, w * 64, lr, lg, w1buf[0]);
  wload<256, 4>(Wp1, 1, w * 64, lr, lg, w1buf[1]);
  {
#pragma unroll
    for (int it = 0; it < 12; ++it) {
      int f2 = sl8 + it * 8;
      uint32_t p = 0;
      if (f2 < 81) p = pack2(sv[it].x, sv[it].y);
      if (f2 < 96) *reinterpret_cast<uint32_t*>(lds + swz_byte(srow, f2 * 2)) = p;
    }
  }
  __syncthreads();                                   // (1)

  // ---- GEMM1: h1 = relu(W1^T x^T + b1), K=192, A -> B
  bf16x8 w2buf[2][4];
  {
    f32x4 acc[4][2];
    acc_bias_init<4>(b1, w * 64, lg, acc);
    gemm_roll<6, 256, 4>(lds, 0, Wp1, w * 64, lr, lg, acc, w1buf);
    wload<256, 4>(Wp2, 0, w * 64, lr, lg, w2buf[0]);  // prefetch G2 kb0,1
    wload<256, 4>(Wp2, 1, w * 64, lr, lg, w2buf[1]);
    epi_relu_store<4>(lds, OFF_B, w * 64, lr, lg, acc);
  }
  __syncthreads();                                   // (2)

  // ---- GEMM2: h2 = relu(W2^T h1^T + b2), K=256, B -> A (Yh dead)
  bf16x8 wh[8];
  {
    f32x4 acc[4][2];
    acc_bias_init<4>(b2, w * 64, lg, acc);
    gemm_roll<8, 256, 4>(lds, OFF_B, Wp2, w * 64, lr, lg, acc, w2buf);
#pragma unroll
    for (int kb = 0; kb < 8; ++kb)                    // prefetch heads (8 frags)
      wh[kb] = *reinterpret_cast<const bf16x8*>(Wpab + ((kb * 64 + 16 * w + lr) << 5) + 8 * lg);
    epi_relu_store<4>(lds, 0, w * 64, lr, lg, acc);
  }
  __syncthreads();                                   // (3)

  // ---- heads: alpha/beta; v -> vbuf (in B, h1 dead). wave w: oc 16w..16w+15
  float regA0[2], regA1[2], regB0[2], regB1[2];
  const int j0 = 8 * w + 2 * lg;
  bf16x8 w4[4];
  bf16x8 w5buf[2][3];
  {
    bool jv = (j0 < K_DIM);
    float ba0 = jv ? ba[j0] : 0.f,     bb0 = jv ? bb[j0] : 0.f;
    float ba1 = jv ? ba[j0 + 1] : 0.f, bb1 = jv ? bb[j0 + 1] : 0.f;
    f32x4 acc[2];
    f32x4 binit = {ba0, bb0, ba1, bb1};
    acc[0] = binit; acc[1] = binit;
    int bE[2], bO[2];
#pragma unroll
    for (int nr = 0; nr < 2; ++nr) {
      bE[nr] = swz_byte(16 * nr + lr, 8 * lg);
      bO[nr] = swz_byte(16 * nr + lr, 32 + 8 * lg);
    }
#pragma unroll
    for (int kb = 0; kb < 8; ++kb) {
#pragma unroll
      for (int nr = 0; nr < 2; ++nr) {
        int base = (kb & 1) ? bO[nr] : bE[nr];
        bf16x8 hf = *reinterpret_cast<const bf16x8*>(lds + base + (kb >> 1) * 128);
        acc[nr] = __builtin_amdgcn_mfma_f32_16x16x32_bf16(wh[kb], hf, acc[nr], 0, 0, 0);
      }
    }
    wload<256, 4>(Wpd1, 0, w * 64, lr, lg, w4);       // prefetch G4
    wload<192, 3>(Wpd2, 0, 48 * w, lr, lg, w5buf[0]); // prefetch G5 kb0,1
    wload<192, 3>(Wpd2, 1, 48 * w, lr, lg, w5buf[1]);

    float uu  = u[0] * 0.98f + 0.01f;
    float l2u = log2f(uu);
    float* vbuf = reinterpret_cast<float*>(lds + OFF_B);
#pragma unroll
    for (int nr = 0; nr < 2; ++nr) {
      int row = 16 * nr + lr;
      float a0  = softplus_f(acc[nr][0]) + 1e-4f;
      float b0v = softplus_f(acc[nr][1]) + 1e-4f;
      float a1  = softplus_f(acc[nr][2]) + 1e-4f;
      float b1v = softplus_f(acc[nr][3]) + 1e-4f;
      regA0[nr] = a0; regB0[nr] = b0v; regA1[nr] = a1; regB1[nr] = b1v;
      if (jv) {
        if (j0 < K_DIM - 1) {
          float t = exp2f(l2u / b0v);
          vbuf[row * 33 + j0] = exp2f(log2f(1.f - t) / a0);
        }
        if (j0 + 1 < K_DIM - 1) {
          float t = exp2f(l2u / b1v);
          vbuf[row * 33 + j0 + 1] = exp2f(log2f(1.f - t) / a1);
        }
      }
    }
  }
  __syncthreads();                                   // (4)

  // ---- stick-breaking scan: thread t<32 owns row t (others wait w/ loads in flight)
  if (tid < ROWS) {
    const float* vbuf = reinterpret_cast<const float*>(lds + OFF_B);
    bf16_t* piT = reinterpret_cast<bf16_t*>(lds + OFF_PI);
    int row = tid;
    float ex = 1.f;
#pragma unroll
    for (int j = 0; j < K_DIM - 1; ++j) {
      float vj = vbuf[row * 33 + j];
      float pi = vj * ex;
      piT[row * 40 + j] = __float2bfloat16(pi);
      ex *= (1.f - vj);
    }
    piT[row * 40 + (K_DIM - 1)] = __float2bfloat16(ex);
    piT[row * 40 + 30] = __float2bfloat16(0.f);
    piT[row * 40 + 31] = __float2bfloat16(0.f);
  }
  __syncthreads();                                   // (5)

  // ---- GEMM4: d = relu(Wd1^T pi^T + bd1), K=32, piT(B) -> A (h2 dead)
  {
    f32x4 acc[4][2];
    acc_bias_init<4>(bd1, w * 64, lg, acc);
    bf16x8 pf[2];
#pragma unroll
    for (int nr = 0; nr < 2; ++nr)
      pf[nr] = *reinterpret_cast<const bf16x8*>(lds + OFF_PI + (16 * nr + lr) * 80 + 16 * lg);
#pragma unroll
    for (int mo = 0; mo < 4; ++mo)
#pragma unroll
      for (int nr = 0; nr < 2; ++nr)
        acc[mo][nr] = __builtin_amdgcn_mfma_f32_16x16x32_bf16(w4[mo], pf[nr], acc[mo][nr], 0, 0, 0);
    epi_relu_store<4>(lds, 0, w * 64, lr, lg, acc);
  }
  __syncthreads();                                   // (6)

  // ---- GEMM5: recon = sigmoid(Wd2^T d^T + bd2); wave w: oc 48w.. (pad 192)
  {
    f32x4 acc[3][2];
#pragma unroll
    for (int mo = 0; mo < 3; ++mo) {
      int col0 = 48 * w + 16 * mo + 4 * lg;
      f32x4 t;
#pragma unroll
      for (int i = 0; i < 4; ++i) t[i] = (col0 + i < D_IN) ? bd2[col0 + i] : 0.f;
#pragma unroll
      for (int nr = 0; nr < 2; ++nr) acc[mo][nr] = t;
    }
    gemm_roll<8, 192, 3>(lds, 0, Wpd2, 48 * w, lr, lg, acc, w5buf);
#pragma unroll
    for (int mo = 0; mo < 3; ++mo) {
      int col0 = 48 * w + 16 * mo + 4 * lg;
#pragma unroll
      for (int nr = 0; nr < 2; ++nr) {
        int row = 16 * nr + lr;
        float s0 = 1.f / (1.f + __expf(-acc[mo][nr][0]));
        float s1 = 1.f / (1.f + __expf(-acc[mo][nr][1]));
        float s2 = 1.f / (1.f + __expf(-acc[mo][nr][2]));
        float s3 = 1.f / (1.f + __expf(-acc[mo][nr][3]));
        float* dst = outRecon + (size_t)(r0 + row) * D_IN + col0;
        if (col0 < D_IN)     *reinterpret_cast<float2*>(dst)     = make_float2(s0, s1);
        if (col0 + 2 < D_IN) *reinterpret_cast<float2*>(dst + 2) = make_float2(s2, s3);
      }
    }
  }

  // ---- deferred global stores (no further barriers) ----
  if (j0 < K_DIM) {
#pragma unroll
    for (int nr = 0; nr < 2; ++nr) {
      int row = 16 * nr + lr;
      size_t base = (size_t)(r0 + row) * K_DIM + j0;
      *reinterpret_cast<float2*>(outAlpha + base) = make_float2(regA0[nr], regA1[nr]);
      *reinterpret_cast<float2*>(outBeta  + base) = make_float2(regB0[nr], regB1[nr]);
    }
  }
  {
    int row = tid >> 3, l8 = tid & 7;
#pragma unroll
    for (int half = 0; half < 2; ++half) {
      int f2 = l8 + half * 8;
      if (f2 < 15) {
        uint32_t pp = *reinterpret_cast<const uint32_t*>(lds + OFF_PI + row * 80 + f2 * 4);
        *reinterpret_cast<float2*>(outPi + (size_t)(r0 + row) * K_DIM + f2 * 2) =
            make_float2(unpk_lo(pp), unpk_hi(pp));
      }
    }
  }
}

extern "C" void kernel_launch(void* const* d_in, const int* in_sizes, int n_in,
                              void* d_out, int out_size, void* d_ws, size_t ws_size,
                              hipStream_t stream) {
  const float* Yh  = (const float*)d_in[0];
  const float* u   = (const float*)d_in[1];
  const float* W1  = (const float*)d_in[2];
  const float* b1  = (const float*)d_in[3];
  const float* W2  = (const float*)d_in[4];
  const float* b2  = (const float*)d_in[5];
  const float* Wa  = (const float*)d_in[6];
  const float* ba  = (const float*)d_in[7];
  const float* Wb  = (const float*)d_in[8];
  const float* bb  = (const float*)d_in[9];
  const float* Wd1 = (const float*)d_in[10];
  const float* bd1 = (const float*)d_in[11];
  const float* Wd2 = (const float*)d_in[12];
  const float* bd2 = (const float*)d_in[13];

  bf16_t* ws   = (bf16_t*)d_ws;
  bf16_t* Wp1  = ws;                  // 6*256*32 = 49152 elems
  bf16_t* Wp2  = Wp1 + 49152;         // 8*256*32 = 65536
  bf16_t* Wpab = Wp2 + 65536;         // 8*64*32  = 16384 (interleaved a/b)
  bf16_t* Wpd1 = Wpab + 16384;        // 1*256*32 = 8192
  bf16_t* Wpd2 = Wpd1 + 8192;         // 8*192*32 = 49152

  float* outRecon = (float*)d_out;
  float* outAlpha = outRecon + (size_t)N_ROWS * D_IN;
  float* outBeta  = outAlpha + (size_t)N_ROWS * K_DIM;
  float* outPi    = outBeta  + (size_t)N_ROWS * K_DIM;

  pack_b_kernel<<<192, 256, 0, stream>>>(W1, Wp1, 162, 256, 256, 6);
  pack_b_kernel<<<256, 256, 0, stream>>>(W2, Wp2, 256, 256, 256, 8);
  pack_ab_kernel<<<64, 256, 0, stream>>>(Wa, Wb, Wpab);
  pack_b_kernel<<<32, 256, 0, stream>>>(Wd1, Wpd1, 30, 256, 256, 1);
  pack_b_kernel<<<192, 256, 0, stream>>>(Wd2, Wpd2, 256, 162, 192, 8);

  usdn_fused<<<N_ROWS / ROWS, 256, 0, stream>>>(Yh, u, b1, b2, ba, bb, bd1, bd2,
                                                Wp1, Wp2, Wpab, Wpd1, Wpd2,
                                                outRecon, outAlpha, outBeta, outPi);
}